// Round 12
// baseline (14718.877 us; speedup 1.0000x reference)
//
#include <hip/hip_runtime.h>
#include <hip/hip_cooperative_groups.h>
#include <math.h>

typedef unsigned int u32x4 __attribute__((ext_vector_type(4)));
typedef unsigned long long ull;

constexpr int T = 4096;   // SEQ_LEN
constexpr int R = 2048;   // RES_SIZE
constexpr int J = 128;    // INPUT_SIZE
constexpr float ONE_MINUS_LEAK = 0.1f;
constexpr float LEAK = 0.9f;
constexpr float INV_SQRT_R = 0.022097086912079608f;  // 1/sqrt(2048)

constexpr int NWG  = 64;   // rendezvous participants (R11-proven floor)
constexpr int NREP = 2;    // 32 sharers per slot line (R5/R11 sweet spot)

// ---------------- Kernel A: proj[t][r] = input[t] . W_in[r] + bias[r] -> d_out
__global__ __launch_bounds__(256) void esn_proj_kernel(
    const float* __restrict__ U, const float* __restrict__ Win,
    const float* __restrict__ bias, float* __restrict__ out)
{
    __shared__ float As[16][129];
    __shared__ float Bs[16][129];
    const int tb = blockIdx.x * 16;
    const int rb = blockIdx.y * 16;
    const int tid = threadIdx.x;

    for (int i = tid; i < 16 * J; i += 256) {
        int r = i >> 7, c = i & 127;
        As[r][c] = U[(size_t)(tb + r) * J + c];
        Bs[r][c] = Win[(size_t)(rb + r) * J + c];
    }
    __syncthreads();

    const int ti = tid >> 4;
    const int rj = tid & 15;
    float acc = 0.f;
#pragma unroll
    for (int k = 0; k < J; ++k) acc = fmaf(As[ti][k], Bs[rj][k], acc);
    out[(size_t)(tb + ti) * R + (rb + rj)] = acc + bias[rb + rj];
}

// ---------------- Kernel B: R11's protocol, 1024-thread WGs, 2 rows/wave.
// 64 WGs x 1024 threads; WG w owns rows [32w, 32w+32); wave v (0..15) owns
// rows rowbase = 32w+2v, +1. slots[2][NREP][R] ull: lo32 = f32 bits,
// hi32 = tag (step index). Publish = one 8B sc0sc1 store per replica from
// lanes 0..1. Poll: thread owns slots {2tid, 2tid+1} -> ONE dwordx4/sweep.
// Skew<=1 tag induction identical to R4/R5/R11.
__global__ __launch_bounds__(1024) void esn_recur_kernel(
    const float* __restrict__ Wres, float* __restrict__ out,
    ull* __restrict__ slots /* [2][NREP][R] */)
{
    const int wg   = blockIdx.x;
    const int tid  = threadIdx.x;
    const int wv   = tid >> 6;              // wave 0..15
    const int lane = tid & 63;
    const int rowbase = wg * 32 + wv * 2;   // this wave's 2 rows
    const int rep  = wg & (NREP - 1);

    // 2 rows of weights in registers (coalesced: 64 lanes x f32 per k).
    float w0[32], w1[32];
    {
        const float* wr0 = Wres + (size_t)(rowbase + 0) * R + lane;
        const float* wr1 = Wres + (size_t)(rowbase + 1) * R + lane;
#pragma unroll
        for (int k = 0; k < 32; ++k) { w0[k] = wr0[k * 64]; w1[k] = wr1[k * 64]; }
    }

    __shared__ __align__(16) float xs[2][R];
    float xold = 0.f;    // lanes 0..1: previous state of row rowbase+lane
    long  spin = 0;      // cumulative guard: bugs -> fast wrong answer

    for (int t = 0; t < T; ++t) {
        // Input projection prefetch (latency hides under the poll).
        float proj = (lane < 2) ? out[(size_t)t * R + rowbase + lane] : 0.f;

        // ---- Poll x^{(t)}: thread owns slots {2tid, 2tid+1}.
        const ull* src = slots + ((size_t)((t & 1) * NREP + rep)) * R;
        const ull* p0 = src + 2 * tid;
        const unsigned want = (unsigned)t;
        u32x4 v0;
        while (true) {
            asm volatile(
                "global_load_dwordx4 %0, %1, off sc0 sc1\n\t"
                "s_waitcnt vmcnt(0)"
                : "=&v"(v0) : "v"(p0) : "memory");
            if (v0[1] == want && v0[3] == want) break;
            if (++spin > (1L << 26)) break;
        }
        float* xb = xs[t & 1];
        *(float2*)&xb[2 * tid] = make_float2(__uint_as_float(v0[0]),
                                            __uint_as_float(v0[2]));
        __syncthreads();   // the only barrier per step: stage -> dot join

        // ---- 2-row dot: one LDS read per k shared by both rows' FMAs.
        const float* x = xs[t & 1];
        float a0 = 0.f, a1 = 0.f, b0 = 0.f, b1 = 0.f;
#pragma unroll
        for (int k = 0; k < 16; ++k) {
            const float xk0 = x[(2 * k + 0) * 64 + lane];
            const float xk1 = x[(2 * k + 1) * 64 + lane];
            a0 = fmaf(w0[2 * k + 0], xk0, a0);
            a1 = fmaf(w0[2 * k + 1], xk1, a1);
            b0 = fmaf(w1[2 * k + 0], xk0, b0);
            b1 = fmaf(w1[2 * k + 1], xk1, b1);
        }
        float accA = a0 + a1;
        float accB = b0 + b1;
#pragma unroll
        for (int off = 32; off > 0; off >>= 1) {
            accA += __shfl_xor(accA, off);
            accB += __shfl_xor(accB, off);
        }
        const float mysum = (lane == 0) ? accA : accB;

        // ---- Lanes 0..1 finalize their row, publish, write output.
        if (lane < 2) {
            const float pre  = mysum + proj;     // proj includes bias
            const float xnew = ONE_MINUS_LEAK * xold +
                               LEAK * erff(pre) * INV_SQRT_R;
            xold = xnew;
            const ull packed = ((ull)(unsigned)(t + 1) << 32) |
                               (ull)__float_as_uint(xnew);
            const size_t pb = (size_t)(((t + 1) & 1) * NREP) * R
                            + rowbase + lane;
#pragma unroll
            for (int g = 0; g < NREP; ++g)
                __hip_atomic_store(&slots[pb + (size_t)g * R], packed,
                                   __ATOMIC_RELAXED, __HIP_MEMORY_SCOPE_AGENT);
            out[(size_t)t * R + rowbase + lane] = xnew;  // states output
        }
    }
}

extern "C" void kernel_launch(void* const* d_in, const int* in_sizes, int n_in,
                              void* d_out, int out_size, void* d_ws, size_t ws_size,
                              hipStream_t stream) {
    const float* U    = (const float*)d_in[0];  // (4096,128)
    const float* Win  = (const float*)d_in[1];  // (2048,128)
    const float* Wres = (const float*)d_in[2];  // (2048,2048)
    const float* bias = (const float*)d_in[3];  // (2048,)
    float* out = (float*)d_out;                 // (4096,2048)
    ull* slots = (ull*)d_ws;                    // [2][NREP][R]

    // tag0/value0 everywhere == valid x^0 = 0 in buf[0]; graph-replay safe.
    hipMemsetAsync(slots, 0, (size_t)2 * NREP * R * sizeof(ull), stream);

    dim3 pgrid(T / 16, R / 16);
    esn_proj_kernel<<<pgrid, dim3(256), 0, stream>>>(U, Win, bias, out);

    void* args[] = { (void*)&Wres, (void*)&out, (void*)&slots };
    hipLaunchCooperativeKernel((const void*)esn_recur_kernel,
                               dim3(NWG), dim3(1024), args, 0, stream);
}

// Round 13
// 11959.250 us; speedup vs baseline: 1.2308x; 1.2308x over previous
//
#include <hip/hip_runtime.h>
#include <hip/hip_cooperative_groups.h>
#include <math.h>

typedef unsigned int u32x4 __attribute__((ext_vector_type(4)));

constexpr int T = 4096;   // SEQ_LEN
constexpr int R = 2048;   // RES_SIZE
constexpr int J = 128;    // INPUT_SIZE
constexpr float ONE_MINUS_LEAK = 0.1f;
constexpr float LEAK = 0.9f;
constexpr float INV_SQRT_R = 0.022097086912079608f;  // 1/sqrt(2048)

constexpr int NWG  = 64;   // rendezvous participants (R11-proven optimum)
constexpr int NREP = 2;    // slot replicas (R5/R11 sweet spot)

// ---------------- Kernel A: proj[t][r] = input[t] . W_in[r] + bias[r] -> d_out
__global__ __launch_bounds__(256) void esn_proj_kernel(
    const float* __restrict__ U, const float* __restrict__ Win,
    const float* __restrict__ bias, float* __restrict__ out)
{
    __shared__ float As[16][129];
    __shared__ float Bs[16][129];
    const int tb = blockIdx.x * 16;
    const int rb = blockIdx.y * 16;
    const int tid = threadIdx.x;

    for (int i = tid; i < 16 * J; i += 256) {
        int r = i >> 7, c = i & 127;
        As[r][c] = U[(size_t)(tb + r) * J + c];
        Bs[r][c] = Win[(size_t)(rb + r) * J + c];
    }
    __syncthreads();

    const int ti = tid >> 4;
    const int rj = tid & 15;
    float acc = 0.f;
#pragma unroll
    for (int k = 0; k < J; ++k) acc = fmaf(As[ti][k], Bs[rj][k], acc);
    out[(size_t)(tb + ti) * R + (rb + rj)] = acc + bias[rb + rj];
}

// ---------------- Kernel B: R11's protocol with 4B tagged-f32 slots.
// 64 WGs x 512 threads; WG w owns rows [32w,32w+32); wave v owns 4 rows.
// slots[2][NREP][R] u32: bits[31:8] = f32 value (low mantissa byte stolen),
// bits[7:0] = tag (t & 0xFF). Quantization ~3e-7 abs/elem -- negligible vs
// the 4.4e-4 threshold. Skew<=1 (R4/R5/R11 induction) => live tags differ
// by <=2, so the 8-bit tag is unambiguous. Each thread polls 4 slots with
// ONE dwordx4 (16B) -> grid sweep traffic 4x lower than R11's.
__global__ __launch_bounds__(512) void esn_recur_kernel(
    const float* __restrict__ Wres, float* __restrict__ out,
    unsigned* __restrict__ slots /* [2][NREP][R] */)
{
    const int wg   = blockIdx.x;
    const int tid  = threadIdx.x;
    const int wv   = tid >> 6;
    const int lane = tid & 63;
    const int rowbase = wg * 32 + wv * 4;   // this wave's 4 rows
    const int rep  = wg & (NREP - 1);

    // 4 rows of weights in registers (coalesced: 64 lanes x f32 per k).
    float w[4][32];
#pragma unroll
    for (int j = 0; j < 4; ++j) {
        const float* wr = Wres + (size_t)(rowbase + j) * R + lane;
#pragma unroll
        for (int k = 0; k < 32; ++k) w[j][k] = wr[k * 64];
    }

    __shared__ __align__(16) float xs[2][R];
    float xold = 0.f;    // lanes 0..3: previous state of row rowbase+lane
    long  spin = 0;      // cumulative guard: bugs -> fast wrong answer

    for (int t = 0; t < T; ++t) {
        // Input projection prefetch (latency hides under the poll).
        float proj = (lane < 4) ? out[(size_t)t * R + rowbase + lane] : 0.f;

        // ---- Poll x^{(t)}: thread owns slots 4tid..4tid+3 -> ONE dwordx4.
        const unsigned* p =
            slots + ((size_t)((t & 1) * NREP + rep)) * R + 4 * tid;
        const unsigned want = (unsigned)t & 0xFFu;
        u32x4 v;
        while (true) {
            asm volatile(
                "global_load_dwordx4 %0, %1, off sc0 sc1\n\t"
                "s_waitcnt vmcnt(0)"
                : "=&v"(v) : "v"(p) : "memory");
            if ((v[0] & 0xFFu) == want && (v[1] & 0xFFu) == want &&
                (v[2] & 0xFFu) == want && (v[3] & 0xFFu) == want) break;
            if (++spin > (1L << 26)) break;
        }
        // Strip tags, stage 16B to LDS.
        float4 xv = make_float4(__uint_as_float(v[0] & 0xFFFFFF00u),
                                __uint_as_float(v[1] & 0xFFFFFF00u),
                                __uint_as_float(v[2] & 0xFFFFFF00u),
                                __uint_as_float(v[3] & 0xFFFFFF00u));
        *(float4*)&xs[t & 1][4 * tid] = xv;
        __syncthreads();   // the only barrier per step: stage -> dot join

        // ---- x into registers once (2-way LDS alias: free), reuse 4 rows.
        const float* x = xs[t & 1];
        float xr[32];
#pragma unroll
        for (int k = 0; k < 32; ++k) xr[k] = x[k * 64 + lane];

        float mysum = 0.f;
#pragma unroll
        for (int j = 0; j < 4; ++j) {
            float a0 = 0.f, a1 = 0.f, a2 = 0.f, a3 = 0.f;
#pragma unroll
            for (int k = 0; k < 8; ++k) {
                a0 = fmaf(w[j][4 * k + 0], xr[4 * k + 0], a0);
                a1 = fmaf(w[j][4 * k + 1], xr[4 * k + 1], a1);
                a2 = fmaf(w[j][4 * k + 2], xr[4 * k + 2], a2);
                a3 = fmaf(w[j][4 * k + 3], xr[4 * k + 3], a3);
            }
            float acc = (a0 + a1) + (a2 + a3);
#pragma unroll
            for (int off = 32; off > 0; off >>= 1)
                acc += __shfl_xor(acc, off);
            if (lane == j) mysum = acc;          // static j -> cndmask
        }

        // ---- Lanes 0..3 finalize their row, publish, write output.
        if (lane < 4) {
            const float pre  = mysum + proj;     // proj includes bias
            const float xnew = ONE_MINUS_LEAK * xold +
                               LEAK * erff(pre) * INV_SQRT_R;
            xold = xnew;
            // Pack: round-to-nearest on the stolen byte, then insert tag.
            const unsigned bits =
                ((__float_as_uint(xnew) + 0x80u) & 0xFFFFFF00u) |
                ((unsigned)(t + 1) & 0xFFu);
            const size_t pb = (size_t)(((t + 1) & 1) * NREP) * R
                            + rowbase + lane;
#pragma unroll
            for (int g = 0; g < NREP; ++g)
                __hip_atomic_store(&slots[pb + (size_t)g * R], bits,
                                   __ATOMIC_RELAXED, __HIP_MEMORY_SCOPE_AGENT);
            out[(size_t)t * R + rowbase + lane] = xnew;  // states output
        }
    }
}

extern "C" void kernel_launch(void* const* d_in, const int* in_sizes, int n_in,
                              void* d_out, int out_size, void* d_ws, size_t ws_size,
                              hipStream_t stream) {
    const float* U    = (const float*)d_in[0];  // (4096,128)
    const float* Win  = (const float*)d_in[1];  // (2048,128)
    const float* Wres = (const float*)d_in[2];  // (2048,2048)
    const float* bias = (const float*)d_in[3];  // (2048,)
    float* out = (float*)d_out;                 // (4096,2048)
    unsigned* slots = (unsigned*)d_ws;          // [2][NREP][R] u32

    // All-zero slots: tag 0 == (t=0)&0xFF, value bits 0 == x^0 = 0. Valid.
    hipMemsetAsync(slots, 0, (size_t)2 * NREP * R * sizeof(unsigned), stream);

    dim3 pgrid(T / 16, R / 16);
    esn_proj_kernel<<<pgrid, dim3(256), 0, stream>>>(U, Win, bias, out);

    void* args[] = { (void*)&Wres, (void*)&out, (void*)&slots };
    hipLaunchCooperativeKernel((const void*)esn_recur_kernel,
                               dim3(NWG), dim3(512), args, 0, stream);
}